// Round 3
// baseline (920.203 us; speedup 1.0000x reference)
//
#include <hip/hip_runtime.h>

// ---------------------------------------------------------------------------
// Separate_68573447847976: dual masked attention (N=9216, C=128) + 3x3 conv.
// All matmuls via v_mfma_f32_16x16x32_bf16 with verified gfx950 layouts:
//   A-frag: A[m=lane&15][k=quad*8+j]   (16B contiguous in k)
//   B-frag: B[k=quad*8+j][n=lane&15]   (16B contiguous in k of the n-column)
//   C/D   : col=lane&15, row=quad*4+reg
// SCALE*log2(e) folded into Q so softmax uses exp2. No online max (logits
// bounded ~|2| by the 0.02-scaled weights; softmax shift-invariant).
// Flash v3: block = 64 q-rows (4 waves x 16), waves share a 1/4 key-range
// (L1 broadcast); S^T computed (swap MFMA args) so P packs into dword pairs
// for a 2x ds_write_b64 + 1x ds_read_b128 transpose. Plain-sum partials to
// global U/L, merged by k_merge (no max bookkeeping needed).
// ---------------------------------------------------------------------------

typedef unsigned short u16;
typedef short bf16x8 __attribute__((ext_vector_type(8)));
typedef float f32x4 __attribute__((ext_vector_type(4)));

#define MFMA(a, b, c) __builtin_amdgcn_mfma_f32_16x16x32_bf16((a), (b), (c), 0, 0, 0)

#define NN 9216   // H*W
#define CC 128

__device__ __forceinline__ u16 f2b(float f) {
  union { float f; unsigned int u; } v; v.f = f;
  unsigned int u = v.u + 0x7fffu + ((v.u >> 16) & 1u);  // RNE
  return (u16)(u >> 16);
}

__device__ __forceinline__ unsigned int f2b2(float lo, float hi) {
  return (unsigned int)f2b(lo) | ((unsigned int)f2b(hi) << 16);
}

__device__ __forceinline__ bf16x8 ldb(const u16* p) { return *(const bf16x8*)p; }

// ---------------- prep: transpose [C][N] f32 -> [N][C] bf16 ----------------
__global__ void k_transpose(const float* __restrict__ x, const float* __restrict__ fm,
                            u16* __restrict__ xt, u16* __restrict__ fmt) {
  __shared__ float tile[32][33];
  const float* src = blockIdx.z ? fm : x;
  u16* dst = blockIdx.z ? fmt : xt;
  int n0 = blockIdx.x * 32, c0 = blockIdx.y * 32;
  int tx = threadIdx.x & 31, ty = threadIdx.x >> 5;  // 32 x 8
#pragma unroll
  for (int i = 0; i < 4; i++)
    tile[ty + i * 8][tx] = src[(c0 + ty + i * 8) * NN + n0 + tx];
  __syncthreads();
#pragma unroll
  for (int i = 0; i < 4; i++)
    dst[(n0 + ty + i * 8) * CC + c0 + tx] = f2b(tile[tx][ty + i * 8]);
}

// ---------------- prep: 8 attention weight mats f32 -> bf16 ----------------
__global__ void k_cvtw(const float* s0, const float* s1, const float* s2, const float* s3,
                       const float* s4, const float* s5, const float* s6, const float* s7,
                       u16* __restrict__ dst) {
  const float* arr[8] = {s0, s1, s2, s3, s4, s5, s6, s7};
  int a = blockIdx.y;
  int i = blockIdx.x * 256 + threadIdx.x;  // 64 blocks * 256 = 16384
  dst[a * 16384 + i] = f2b(arr[a][i]);
}

// ---------------- prep: conv_w [o][i][3][3] -> [khkw][o][i] bf16 -----------
__global__ void k_cvtconv(const float* __restrict__ cw, u16* __restrict__ wp) {
  int i = blockIdx.x * 256 + threadIdx.x;  // 576 blocks -> 147456
  int khkw = i >> 14; int rem = i & 16383; int o = rem >> 7; int ii = rem & 127;
  wp[i] = f2b(cw[(o * 128 + ii) * 9 + khkw]);
}

// ---------------- QKV projections (MFMA) -----------------------------------
__global__ __launch_bounds__(256) void k_qkv(
    const u16* __restrict__ xt, const u16* __restrict__ fmt, const float* __restrict__ hm,
    const u16* __restrict__ wall, u16* __restrict__ Q, u16* __restrict__ K,
    u16* __restrict__ Vt) {
  int wid = threadIdx.x >> 6, lane = threadIdx.x & 63;
  int quad = lane >> 4, c = lane & 15;
  int nt = blockIdx.x * 4 + wid;  // 0..575
  int arr = blockIdx.y;
  int attn = arr / 3, kind = arr % 3;  // 0=Q 1=K 2=V
  int nb = nt * 16;
  const u16* A = (kind == 1) ? fmt : xt;
  const u16* W = wall + (attn * 4 + kind) * 16384;

  if (kind < 2) {  // D[n][d]
    bf16x8 af[4];
#pragma unroll
    for (int ks = 0; ks < 4; ks++)
      af[ks] = ldb(A + (nb + c) * CC + ks * 32 + quad * 8);
    float msk[4];
#pragma unroll
    for (int r = 0; r < 4; r++) {
      bool obj = hm[nb + quad * 4 + r] > 0.3f;
      float mv = (attn == 0) ? (obj ? 1.f : 0.01f) : (obj ? 0.01f : 1.f);
      msk[r] = (kind == 0) ? mv * 0.3606737602222409f : mv;  // 0.25*log2(e)
    }
    u16* out = (kind == 0 ? Q : K) + attn * NN * CC;
#pragma unroll
    for (int dt = 0; dt < 8; dt++) {
      f32x4 acc = {0.f, 0.f, 0.f, 0.f};
#pragma unroll
      for (int ks = 0; ks < 4; ks++)
        acc = MFMA(af[ks], ldb(W + (dt * 16 + c) * CC + ks * 32 + quad * 8), acc);
#pragma unroll
      for (int r = 0; r < 4; r++)
        out[(nb + quad * 4 + r) * CC + dt * 16 + c] = f2b(acc[r] * msk[r]);
    }
  } else {  // Vt[d][n]
    bf16x8 bfr[4];
#pragma unroll
    for (int ks = 0; ks < 4; ks++)
      bfr[ks] = ldb(A + (nb + c) * CC + ks * 32 + quad * 8);
    bool obj = hm[nb + c] > 0.3f;
    float mv = (attn == 0) ? (obj ? 1.f : 0.01f) : (obj ? 0.01f : 1.f);
    u16* out = Vt + attn * CC * NN;
#pragma unroll
    for (int dt = 0; dt < 8; dt++) {
      f32x4 acc = {0.f, 0.f, 0.f, 0.f};
#pragma unroll
      for (int ks = 0; ks < 4; ks++)
        acc = MFMA(ldb(W + (dt * 16 + c) * CC + ks * 32 + quad * 8), bfr[ks], acc);
#pragma unroll
      for (int r = 0; r < 4; r++)
        out[(dt * 16 + quad * 4 + r) * NN + nb + c] = f2b(acc[r] * mv);
    }
  }
}

// ---------------- flash v3 --------------------------------------------------
// grid 1152: b = (attn*4 + ks)*144 + qt. Block = 64 q-rows (wave wid owns 16),
// keys [ks*2304, +2304) swept by ALL 4 waves together (L1 reuse).
// S^T = MFMA(kf, qf); P^T packed to LDS rows [q][k/2] (stride 10 uint2);
// pf read back in A-layout; O += pf*V; rowsum via MFMA(pf, ONES).
// Partial (unnormalized) U f32 + rowsum L f32 to global; merged later.
__global__ __launch_bounds__(256, 3) void k_flash(
    const u16* __restrict__ Q, const u16* __restrict__ K, const u16* __restrict__ Vt,
    float* __restrict__ U, float* __restrict__ L) {
  __shared__ uint2 Pl[4][160];  // per-wave, row q: stride 10 uint2 (80 B)
  int tid = threadIdx.x;
  int wid = tid >> 6, lane = tid & 63;
  int quad = lane >> 4, c = lane & 15;
  int b = blockIdx.x;
  int qt = b % 144; int r1 = b / 144;
  int ks = r1 & 3; int attn = r1 >> 2;
  int nb = qt * 64 + wid * 16;
  const u16* q = Q + attn * NN * CC;
  const u16* k = K + attn * NN * CC;
  const u16* v = Vt + attn * CC * NN;
  int kb0 = ks * 2304;

  bf16x8 qf[4];
#pragma unroll
  for (int k4 = 0; k4 < 4; k4++)
    qf[k4] = ldb(q + (nb + c) * CC + k4 * 32 + quad * 8);

  const bf16x8 ONES = {(short)0x3F80, (short)0x3F80, (short)0x3F80, (short)0x3F80,
                       (short)0x3F80, (short)0x3F80, (short)0x3F80, (short)0x3F80};

  f32x4 O[8];
  f32x4 lacc = {0.f, 0.f, 0.f, 0.f};
#pragma unroll
  for (int dt = 0; dt < 8; dt++) O[dt] = (f32x4){0.f, 0.f, 0.f, 0.f};

  uint2* Pw = &Pl[wid][0];
  for (int it = 0; it < 72; it++) {
    int kb = kb0 + it * 32;
    bf16x8 kf[2][4], vf[8];
#pragma unroll
    for (int kt = 0; kt < 2; kt++)
#pragma unroll
      for (int k4 = 0; k4 < 4; k4++)
        kf[kt][k4] = ldb(k + (kb + kt * 16 + c) * CC + k4 * 32 + quad * 8);
#pragma unroll
    for (int dt = 0; dt < 8; dt++)
      vf[dt] = ldb(v + (dt * 16 + c) * NN + kb + quad * 8);

    // S^T tiles: lane (quad,c) reg r = S[q=c][k = kb + kt*16 + quad*4 + r]
    f32x4 s0 = {0.f, 0.f, 0.f, 0.f}, s1 = {0.f, 0.f, 0.f, 0.f};
#pragma unroll
    for (int k4 = 0; k4 < 4; k4++) {
      s0 = MFMA(kf[0][k4], qf[k4], s0);
      s1 = MFMA(kf[1][k4], qf[k4], s1);
    }
    // exp2 + pack 4 consecutive-k bf16 into a uint2 per kt
    uint2 d0, d1;
    d0.x = f2b2(exp2f(s0[0]), exp2f(s0[1]));
    d0.y = f2b2(exp2f(s0[2]), exp2f(s0[3]));
    d1.x = f2b2(exp2f(s1[0]), exp2f(s1[1]));
    d1.y = f2b2(exp2f(s1[2]), exp2f(s1[3]));
    Pw[c * 10 + quad] = d0;       // k = quad*4 .. +3
    Pw[c * 10 + 4 + quad] = d1;   // k = 16 + quad*4 .. +3
    // A-layout read: P[q=c][k = quad*8 .. +7]  (16B-aligned: (c*10+quad*2)*8)
    bf16x8 pf = *(const bf16x8*)&Pw[c * 10 + quad * 2];
    lacc = MFMA(pf, ONES, lacc);
#pragma unroll
    for (int dt = 0; dt < 8; dt++) O[dt] = MFMA(pf, vf[dt], O[dt]);
  }

  float* up = U + ((long)((attn * 4 + ks) * NN + nb)) * CC;
#pragma unroll
  for (int dt = 0; dt < 8; dt++)
#pragma unroll
    for (int r = 0; r < 4; r++)
      up[(quad * 4 + r) * CC + dt * 16 + c] = O[dt][r];
  if (c == 0) {
#pragma unroll
    for (int r = 0; r < 4; r++)
      L[(attn * 4 + ks) * NN + nb + quad * 4 + r] = lacc[r];
  }
}

// ---------------- merge 4 key-split partials, normalize, -> bf16 ------------
__global__ void k_merge(const float* __restrict__ U, const float* __restrict__ L,
                        u16* __restrict__ Om) {
  int t = blockIdx.x * 256 + threadIdx.x;  // 2304 blocks -> 2*9216*32
  int attn = t / (NN * 32); int rem = t % (NN * 32);
  int n = rem >> 5; int d4 = (rem & 31) * 4;
  f32x4 acc = {0.f, 0.f, 0.f, 0.f};
  float l = 0.f;
#pragma unroll
  for (int s = 0; s < 4; s++) {
    long base = (long)((attn * 4 + s) * NN + n);
    f32x4 u = *(const f32x4*)(U + base * CC + d4);
    acc[0] += u[0]; acc[1] += u[1]; acc[2] += u[2]; acc[3] += u[3];
    l += L[base];
  }
  float inv = 1.f / l;
  uint2 pk;
  pk.x = f2b2(acc[0] * inv, acc[1] * inv);
  pk.y = f2b2(acc[2] * inv, acc[3] * inv);
  *(uint2*)(Om + ((long)attn * NN + n) * CC + d4) = pk;
}

// ---------------- output projection (et split across waves) ----------------
// grid 576: block = one 16-row tile; wave wid handles et = wid*2 + {0,1}.
__global__ __launch_bounds__(256) void k_proj(const u16* __restrict__ Om,
                                              const u16* __restrict__ wall,
                                              const float* __restrict__ pb0,
                                              const float* __restrict__ pb1,
                                              u16* __restrict__ amt) {
  int wid = threadIdx.x >> 6, lane = threadIdx.x & 63;
  int quad = lane >> 4, c = lane & 15;
  int nb = blockIdx.x * 16;
  bf16x8 af[2][4];
#pragma unroll
  for (int a = 0; a < 2; a++)
#pragma unroll
    for (int k4 = 0; k4 < 4; k4++)
      af[a][k4] = ldb(Om + ((long)a * NN + nb + c) * CC + k4 * 32 + quad * 8);
  const u16* wpo = wall + 3 * 16384;
  const u16* wpb = wall + 7 * 16384;
#pragma unroll
  for (int eh = 0; eh < 2; eh++) {
    int et = wid * 2 + eh;
    f32x4 acc = {0.f, 0.f, 0.f, 0.f};
#pragma unroll
    for (int k4 = 0; k4 < 4; k4++)
      acc = MFMA(af[0][k4], ldb(wpo + (et * 16 + c) * CC + k4 * 32 + quad * 8), acc);
#pragma unroll
    for (int k4 = 0; k4 < 4; k4++)
      acc = MFMA(af[1][k4], ldb(wpb + (et * 16 + c) * CC + k4 * 32 + quad * 8), acc);
    float bias = pb0[et * 16 + c] + pb1[et * 16 + c];
#pragma unroll
    for (int r = 0; r < 4; r++)
      amt[(nb + quad * 4 + r) * CC + et * 16 + c] = f2b(acc[r] + bias);
  }
}

// ---------------- 3x3 SAME conv (ot split across waves) ---------------------
// grid 576: block = one 16-pixel tile; wave wid handles ot = wid*2 + {0,1}.
__global__ __launch_bounds__(256) void k_conv(const u16* __restrict__ amt,
                                              const u16* __restrict__ wp,
                                              const float* __restrict__ cb,
                                              float* __restrict__ out) {
  int wid = threadIdx.x >> 6, lane = threadIdx.x & 63;
  int quad = lane >> 4, c = lane & 15;
  int p = blockIdx.x * 16 + c;
  int h = p / 96, w = p % 96;
  f32x4 acc[2];
  acc[0] = (f32x4){0.f, 0.f, 0.f, 0.f};
  acc[1] = (f32x4){0.f, 0.f, 0.f, 0.f};
  const bf16x8 zv = {0, 0, 0, 0, 0, 0, 0, 0};
#pragma unroll
  for (int kh = 0; kh < 3; kh++)
#pragma unroll
    for (int kw = 0; kw < 3; kw++) {
      int hh = h + kh - 1, ww = w + kw - 1;
      bool valid = (hh >= 0) && (hh < 96) && (ww >= 0) && (ww < 96);
      int sp = hh * 96 + ww;
      const u16* wbase = wp + (kh * 3 + kw) * 16384;
#pragma unroll
      for (int k4 = 0; k4 < 4; k4++) {
        bf16x8 bv = zv;
        if (valid) bv = ldb(amt + sp * CC + k4 * 32 + quad * 8);
#pragma unroll
        for (int oi = 0; oi < 2; oi++) {
          int ot = wid * 2 + oi;
          acc[oi] = MFMA(ldb(wbase + (ot * 16 + c) * CC + k4 * 32 + quad * 8), bv, acc[oi]);
        }
      }
    }
#pragma unroll
  for (int oi = 0; oi < 2; oi++)
#pragma unroll
    for (int r = 0; r < 4; r++) {
      int o = (wid * 2 + oi) * 16 + quad * 4 + r;
      out[o * NN + p] = acc[oi][r] + cb[o];
    }
}

// ---------------- host ------------------------------------------------------
extern "C" void kernel_launch(void* const* d_in, const int* in_sizes, int n_in,
                              void* d_out, int out_size, void* d_ws, size_t ws_size,
                              hipStream_t stream) {
  (void)in_sizes; (void)n_in; (void)out_size; (void)ws_size;
  const float* x   = (const float*)d_in[0];
  const float* fm  = (const float*)d_in[1];
  const float* hm  = (const float*)d_in[2];
  const float* qw0 = (const float*)d_in[3];
  const float* kw0 = (const float*)d_in[4];
  const float* vw0 = (const float*)d_in[5];
  const float* pw0 = (const float*)d_in[6];
  const float* pb0 = (const float*)d_in[7];
  const float* qw1 = (const float*)d_in[8];
  const float* kw1 = (const float*)d_in[9];
  const float* vw1 = (const float*)d_in[10];
  const float* pw1 = (const float*)d_in[11];
  const float* pb1 = (const float*)d_in[12];
  const float* cw  = (const float*)d_in[13];
  const float* cb  = (const float*)d_in[14];
  float* out = (float*)d_out;
  char* ws = (char*)d_ws;

  // ws layout (bytes). OM overlays QQ (dead after flash); AMT overlays KK.
  u16*   XT   = (u16*)(ws + 0);          //  2359296  [9216][128] bf16
  u16*   FMT  = (u16*)(ws + 2359296);    //  2359296
  u16*   WALL = (u16*)(ws + 4718592);    //   262144  8 x [128][128] bf16
  u16*   WCV  = (u16*)(ws + 4980736);    //   294912  [9][128][128] bf16
  u16*   QQ   = (u16*)(ws + 5275648);    //  4718592  [2][9216][128] bf16
  u16*   KK   = (u16*)(ws + 9994240);    //  4718592
  u16*   VT   = (u16*)(ws + 14712832);   //  4718592  [2][128][9216] bf16
  float* UU   = (float*)(ws + 19431424); // 37748736  [2][4][9216][128] f32
  float* LL   = (float*)(ws + 57180160); //   294912  [2][4][9216] f32
  u16*   OM   = QQ;                      //  4718592  (overlay)
  u16*   AMT  = KK;                      //  2359296  (overlay)
  // total 57475072 bytes

  k_transpose<<<dim3(288, 4, 2), 256, 0, stream>>>(x, fm, XT, FMT);
  k_cvtw<<<dim3(64, 8), 256, 0, stream>>>(qw0, kw0, vw0, pw0, qw1, kw1, vw1, pw1, WALL);
  k_cvtconv<<<576, 256, 0, stream>>>(cw, WCV);
  k_qkv<<<dim3(144, 6), 256, 0, stream>>>(XT, FMT, hm, WALL, QQ, KK, VT);
  k_flash<<<1152, 256, 0, stream>>>(QQ, KK, VT, UU, LL);
  k_merge<<<2304, 256, 0, stream>>>(UU, LL, OM);
  k_proj<<<576, 256, 0, stream>>>(OM, WALL, pb0, pb1, AMT);
  k_conv<<<576, 256, 0, stream>>>(AMT, WCV, cb, out);
}

// Round 4
// 506.388 us; speedup vs baseline: 1.8172x; 1.8172x over previous
//
#include <hip/hip_runtime.h>

// ---------------------------------------------------------------------------
// Separate_68573447847976: dual masked attention (N=9216, C=128) + 3x3 conv.
// All matmuls via v_mfma_f32_16x16x32_bf16 with verified gfx950 layouts:
//   A-frag: A[m=lane&15][k=quad*8+j]   (16B contiguous in k)
//   B-frag: B[k=quad*8+j][n=lane&15]   (16B contiguous in k of the n-column)
//   C/D   : col=lane&15, row=quad*4+reg
// SCALE*log2(e) folded into Q so softmax uses exp2. No online max (logits
// bounded ~|2| by the 0.02-scaled weights; softmax shift-invariant).
// Flash v4: 432 blocks (2 attn x 72 q-groups x keysplit 3). Block = 4 waves,
// wave = 32 q-rows; ALL waves sweep the same 3072-key range (L1 merges the
// duplicate K/V streams). K-frags double-buffered in registers (explicit
// prefetch -> MLP=16 instead of serialized loads, the round-3 killer);
// V-frags issued at iter top, consumed late. S^T computed (swap MFMA args)
// so P packs to dwords: 4x ds_write_b64 + 2x ds_read_b128 per 32 q-rows.
// Partial (unnormalized) U,rowsum L to global f32; k_merge combines 3 splits.
// ---------------------------------------------------------------------------

typedef unsigned short u16;
typedef short bf16x8 __attribute__((ext_vector_type(8)));
typedef float f32x4 __attribute__((ext_vector_type(4)));

#define MFMA(a, b, c) __builtin_amdgcn_mfma_f32_16x16x32_bf16((a), (b), (c), 0, 0, 0)

#define NN 9216   // H*W
#define CC 128

__device__ __forceinline__ u16 f2b(float f) {
  union { float f; unsigned int u; } v; v.f = f;
  unsigned int u = v.u + 0x7fffu + ((v.u >> 16) & 1u);  // RNE
  return (u16)(u >> 16);
}

__device__ __forceinline__ unsigned int f2b2(float lo, float hi) {
  return (unsigned int)f2b(lo) | ((unsigned int)f2b(hi) << 16);
}

__device__ __forceinline__ bf16x8 ldb(const u16* p) { return *(const bf16x8*)p; }

// ---------------- prep: transpose [C][N] f32 -> [N][C] bf16 ----------------
__global__ void k_transpose(const float* __restrict__ x, const float* __restrict__ fm,
                            u16* __restrict__ xt, u16* __restrict__ fmt) {
  __shared__ float tile[32][33];
  const float* src = blockIdx.z ? fm : x;
  u16* dst = blockIdx.z ? fmt : xt;
  int n0 = blockIdx.x * 32, c0 = blockIdx.y * 32;
  int tx = threadIdx.x & 31, ty = threadIdx.x >> 5;  // 32 x 8
#pragma unroll
  for (int i = 0; i < 4; i++)
    tile[ty + i * 8][tx] = src[(c0 + ty + i * 8) * NN + n0 + tx];
  __syncthreads();
#pragma unroll
  for (int i = 0; i < 4; i++)
    dst[(n0 + ty + i * 8) * CC + c0 + tx] = f2b(tile[tx][ty + i * 8]);
}

// ---------------- prep: 8 attention weight mats f32 -> bf16 ----------------
__global__ void k_cvtw(const float* s0, const float* s1, const float* s2, const float* s3,
                       const float* s4, const float* s5, const float* s6, const float* s7,
                       u16* __restrict__ dst) {
  const float* arr[8] = {s0, s1, s2, s3, s4, s5, s6, s7};
  int a = blockIdx.y;
  int i = blockIdx.x * 256 + threadIdx.x;  // 64 blocks * 256 = 16384
  dst[a * 16384 + i] = f2b(arr[a][i]);
}

// ---------------- prep: conv_w [o][i][3][3] -> [khkw][o][i] bf16 -----------
__global__ void k_cvtconv(const float* __restrict__ cw, u16* __restrict__ wp) {
  int i = blockIdx.x * 256 + threadIdx.x;  // 576 blocks -> 147456
  int khkw = i >> 14; int rem = i & 16383; int o = rem >> 7; int ii = rem & 127;
  wp[i] = f2b(cw[(o * 128 + ii) * 9 + khkw]);
}

// ---------------- QKV projections (MFMA) -----------------------------------
__global__ __launch_bounds__(256) void k_qkv(
    const u16* __restrict__ xt, const u16* __restrict__ fmt, const float* __restrict__ hm,
    const u16* __restrict__ wall, u16* __restrict__ Q, u16* __restrict__ K,
    u16* __restrict__ Vt) {
  int wid = threadIdx.x >> 6, lane = threadIdx.x & 63;
  int quad = lane >> 4, c = lane & 15;
  int nt = blockIdx.x * 4 + wid;  // 0..575
  int arr = blockIdx.y;
  int attn = arr / 3, kind = arr % 3;  // 0=Q 1=K 2=V
  int nb = nt * 16;
  const u16* A = (kind == 1) ? fmt : xt;
  const u16* W = wall + (attn * 4 + kind) * 16384;

  if (kind < 2) {  // D[n][d]
    bf16x8 af[4];
#pragma unroll
    for (int ks = 0; ks < 4; ks++)
      af[ks] = ldb(A + (nb + c) * CC + ks * 32 + quad * 8);
    float msk[4];
#pragma unroll
    for (int r = 0; r < 4; r++) {
      bool obj = hm[nb + quad * 4 + r] > 0.3f;
      float mv = (attn == 0) ? (obj ? 1.f : 0.01f) : (obj ? 0.01f : 1.f);
      msk[r] = (kind == 0) ? mv * 0.3606737602222409f : mv;  // 0.25*log2(e)
    }
    u16* out = (kind == 0 ? Q : K) + attn * NN * CC;
#pragma unroll
    for (int dt = 0; dt < 8; dt++) {
      f32x4 acc = {0.f, 0.f, 0.f, 0.f};
#pragma unroll
      for (int ks = 0; ks < 4; ks++)
        acc = MFMA(af[ks], ldb(W + (dt * 16 + c) * CC + ks * 32 + quad * 8), acc);
#pragma unroll
      for (int r = 0; r < 4; r++)
        out[(nb + quad * 4 + r) * CC + dt * 16 + c] = f2b(acc[r] * msk[r]);
    }
  } else {  // Vt[d][n]
    bf16x8 bfr[4];
#pragma unroll
    for (int ks = 0; ks < 4; ks++)
      bfr[ks] = ldb(A + (nb + c) * CC + ks * 32 + quad * 8);
    bool obj = hm[nb + c] > 0.3f;
    float mv = (attn == 0) ? (obj ? 1.f : 0.01f) : (obj ? 0.01f : 1.f);
    u16* out = Vt + attn * CC * NN;
#pragma unroll
    for (int dt = 0; dt < 8; dt++) {
      f32x4 acc = {0.f, 0.f, 0.f, 0.f};
#pragma unroll
      for (int ks = 0; ks < 4; ks++)
        acc = MFMA(ldb(W + (dt * 16 + c) * CC + ks * 32 + quad * 8), bfr[ks], acc);
#pragma unroll
      for (int r = 0; r < 4; r++)
        out[(dt * 16 + quad * 4 + r) * NN + nb + c] = f2b(acc[r] * mv);
    }
  }
}

// ---------------- flash v4 --------------------------------------------------
__global__ __launch_bounds__(256, 2) void k_flash(
    const u16* __restrict__ Q, const u16* __restrict__ K, const u16* __restrict__ Vt,
    float* __restrict__ U, float* __restrict__ L) {
  __shared__ uint2 Pl[4][320];  // per wave: 32 q-rows x stride 10 uint2 (80 B)
  int tid = threadIdx.x;
  int wid = tid >> 6, lane = tid & 63;
  int quad = lane >> 4, c = lane & 15;
  int b = blockIdx.x;                // 432: b = (attn*3 + ks)*72 + qg
  int qg = b % 72; int r1 = b / 72;
  int ks = r1 % 3; int attn = r1 / 3;
  int nb = qg * 128 + wid * 32;      // wave owns 32 q-rows
  const u16* q = Q + attn * NN * CC;
  const u16* k = K + attn * NN * CC;
  const u16* v = Vt + attn * CC * NN;
  int kb0 = ks * 3072;

  bf16x8 qf[2][4];
#pragma unroll
  for (int qt = 0; qt < 2; qt++)
#pragma unroll
    for (int k4 = 0; k4 < 4; k4++)
      qf[qt][k4] = ldb(q + (nb + qt * 16 + c) * CC + k4 * 32 + quad * 8);

  const bf16x8 ONES = {(short)0x3F80, (short)0x3F80, (short)0x3F80, (short)0x3F80,
                       (short)0x3F80, (short)0x3F80, (short)0x3F80, (short)0x3F80};

  f32x4 O[2][8];
  f32x4 lacc[2];
#pragma unroll
  for (int qt = 0; qt < 2; qt++) {
#pragma unroll
    for (int dt = 0; dt < 8; dt++) O[qt][dt] = (f32x4){0.f, 0.f, 0.f, 0.f};
    lacc[qt] = (f32x4){0.f, 0.f, 0.f, 0.f};
  }

  uint2* Pw = &Pl[wid][0];
  bf16x8 kfA[2][4], kfB[2][4];

#define LOAD_KF(DST, KB)                                                      \
  _Pragma("unroll") for (int kt = 0; kt < 2; kt++)                            \
  _Pragma("unroll") for (int k4 = 0; k4 < 4; k4++)                            \
      DST[kt][k4] = ldb(k + ((KB) + kt * 16 + c) * CC + k4 * 32 + quad * 8);

#define FLASH_ITER(CUR, NXT, KB, KBN)                                         \
  {                                                                           \
    bf16x8 vf[8];                                                             \
    _Pragma("unroll") for (int dt = 0; dt < 8; dt++)                          \
        vf[dt] = ldb(v + (dt * 16 + c) * NN + (KB) + quad * 8);               \
    LOAD_KF(NXT, KBN)                                                         \
    _Pragma("unroll") for (int qt = 0; qt < 2; qt++) {                        \
      f32x4 s0 = {0.f, 0.f, 0.f, 0.f}, s1 = {0.f, 0.f, 0.f, 0.f};            \
      _Pragma("unroll") for (int k4 = 0; k4 < 4; k4++) {                      \
        s0 = MFMA(CUR[0][k4], qf[qt][k4], s0);                                \
        s1 = MFMA(CUR[1][k4], qf[qt][k4], s1);                                \
      }                                                                       \
      uint2 d0, d1;                                                           \
      d0.x = f2b2(exp2f(s0[0]), exp2f(s0[1]));                                \
      d0.y = f2b2(exp2f(s0[2]), exp2f(s0[3]));                                \
      d1.x = f2b2(exp2f(s1[0]), exp2f(s1[1]));                                \
      d1.y = f2b2(exp2f(s1[2]), exp2f(s1[3]));                                \
      Pw[(qt * 16 + c) * 10 + quad] = d0;                                     \
      Pw[(qt * 16 + c) * 10 + 4 + quad] = d1;                                 \
    }                                                                         \
    _Pragma("unroll") for (int qt = 0; qt < 2; qt++) {                        \
      bf16x8 pf = *(const bf16x8*)&Pw[(qt * 16 + c) * 10 + quad * 2];         \
      lacc[qt] = MFMA(pf, ONES, lacc[qt]);                                    \
      _Pragma("unroll") for (int dt = 0; dt < 8; dt++)                        \
          O[qt][dt] = MFMA(pf, vf[dt], O[qt][dt]);                            \
    }                                                                         \
  }

  LOAD_KF(kfA, kb0)
  for (int it = 0; it < 96; it += 2) {
    int kb1 = kb0 + it * 32, kb2 = kb0 + (it + 1) * 32;
    int kb3 = (it + 2 < 96) ? kb0 + (it + 2) * 32 : kb0;  // harmless wrap
    FLASH_ITER(kfA, kfB, kb1, kb2)
    FLASH_ITER(kfB, kfA, kb2, kb3)
  }
#undef FLASH_ITER
#undef LOAD_KF

  float* up = U + ((long)((attn * 3 + ks) * NN + nb)) * CC;
#pragma unroll
  for (int qt = 0; qt < 2; qt++)
#pragma unroll
    for (int dt = 0; dt < 8; dt++)
#pragma unroll
      for (int r = 0; r < 4; r++)
        up[(qt * 16 + quad * 4 + r) * CC + dt * 16 + c] = O[qt][dt][r];
  if (c == 0) {
#pragma unroll
    for (int qt = 0; qt < 2; qt++)
#pragma unroll
      for (int r = 0; r < 4; r++)
        L[(attn * 3 + ks) * NN + nb + qt * 16 + quad * 4 + r] = lacc[qt][r];
  }
}

// ---------------- merge 3 key-split partials, normalize, -> bf16 ------------
__global__ void k_merge(const float* __restrict__ U, const float* __restrict__ L,
                        u16* __restrict__ Om) {
  int t = blockIdx.x * 256 + threadIdx.x;  // 2304 blocks -> 2*9216*32
  int attn = t / (NN * 32); int rem = t % (NN * 32);
  int n = rem >> 5; int d4 = (rem & 31) * 4;
  f32x4 acc = {0.f, 0.f, 0.f, 0.f};
  float l = 0.f;
#pragma unroll
  for (int s = 0; s < 3; s++) {
    long base = (long)((attn * 3 + s) * NN + n);
    f32x4 u = *(const f32x4*)(U + base * CC + d4);
    acc[0] += u[0]; acc[1] += u[1]; acc[2] += u[2]; acc[3] += u[3];
    l += L[base];
  }
  float inv = 1.f / l;
  uint2 pk;
  pk.x = f2b2(acc[0] * inv, acc[1] * inv);
  pk.y = f2b2(acc[2] * inv, acc[3] * inv);
  *(uint2*)(Om + ((long)attn * NN + n) * CC + d4) = pk;
}

// ---------------- output projection (et split across waves) ----------------
__global__ __launch_bounds__(256) void k_proj(const u16* __restrict__ Om,
                                              const u16* __restrict__ wall,
                                              const float* __restrict__ pb0,
                                              const float* __restrict__ pb1,
                                              u16* __restrict__ amt) {
  int wid = threadIdx.x >> 6, lane = threadIdx.x & 63;
  int quad = lane >> 4, c = lane & 15;
  int nb = blockIdx.x * 16;
  bf16x8 af[2][4];
#pragma unroll
  for (int a = 0; a < 2; a++)
#pragma unroll
    for (int k4 = 0; k4 < 4; k4++)
      af[a][k4] = ldb(Om + ((long)a * NN + nb + c) * CC + k4 * 32 + quad * 8);
  const u16* wpo = wall + 3 * 16384;
  const u16* wpb = wall + 7 * 16384;
#pragma unroll
  for (int eh = 0; eh < 2; eh++) {
    int et = wid * 2 + eh;
    f32x4 acc = {0.f, 0.f, 0.f, 0.f};
#pragma unroll
    for (int k4 = 0; k4 < 4; k4++)
      acc = MFMA(af[0][k4], ldb(wpo + (et * 16 + c) * CC + k4 * 32 + quad * 8), acc);
#pragma unroll
    for (int k4 = 0; k4 < 4; k4++)
      acc = MFMA(af[1][k4], ldb(wpb + (et * 16 + c) * CC + k4 * 32 + quad * 8), acc);
    float bias = pb0[et * 16 + c] + pb1[et * 16 + c];
#pragma unroll
    for (int r = 0; r < 4; r++)
      amt[(nb + quad * 4 + r) * CC + et * 16 + c] = f2b(acc[r] + bias);
  }
}

// ---------------- 3x3 SAME conv (ot split across waves) ---------------------
__global__ __launch_bounds__(256) void k_conv(const u16* __restrict__ amt,
                                              const u16* __restrict__ wp,
                                              const float* __restrict__ cb,
                                              float* __restrict__ out) {
  int wid = threadIdx.x >> 6, lane = threadIdx.x & 63;
  int quad = lane >> 4, c = lane & 15;
  int p = blockIdx.x * 16 + c;
  int h = p / 96, w = p % 96;
  f32x4 acc[2];
  acc[0] = (f32x4){0.f, 0.f, 0.f, 0.f};
  acc[1] = (f32x4){0.f, 0.f, 0.f, 0.f};
  const bf16x8 zv = {0, 0, 0, 0, 0, 0, 0, 0};
#pragma unroll
  for (int kh = 0; kh < 3; kh++)
#pragma unroll
    for (int kw = 0; kw < 3; kw++) {
      int hh = h + kh - 1, ww = w + kw - 1;
      bool valid = (hh >= 0) && (hh < 96) && (ww >= 0) && (ww < 96);
      int sp = hh * 96 + ww;
      const u16* wbase = wp + (kh * 3 + kw) * 16384;
#pragma unroll
      for (int k4 = 0; k4 < 4; k4++) {
        bf16x8 bv = zv;
        if (valid) bv = ldb(amt + sp * CC + k4 * 32 + quad * 8);
#pragma unroll
        for (int oi = 0; oi < 2; oi++) {
          int ot = wid * 2 + oi;
          acc[oi] = MFMA(ldb(wbase + (ot * 16 + c) * CC + k4 * 32 + quad * 8), bv, acc[oi]);
        }
      }
    }
#pragma unroll
  for (int oi = 0; oi < 2; oi++)
#pragma unroll
    for (int r = 0; r < 4; r++) {
      int o = (wid * 2 + oi) * 16 + quad * 4 + r;
      out[o * NN + p] = acc[oi][r] + cb[o];
    }
}

// ---------------- host ------------------------------------------------------
extern "C" void kernel_launch(void* const* d_in, const int* in_sizes, int n_in,
                              void* d_out, int out_size, void* d_ws, size_t ws_size,
                              hipStream_t stream) {
  (void)in_sizes; (void)n_in; (void)out_size; (void)ws_size;
  const float* x   = (const float*)d_in[0];
  const float* fm  = (const float*)d_in[1];
  const float* hm  = (const float*)d_in[2];
  const float* qw0 = (const float*)d_in[3];
  const float* kw0 = (const float*)d_in[4];
  const float* vw0 = (const float*)d_in[5];
  const float* pw0 = (const float*)d_in[6];
  const float* pb0 = (const float*)d_in[7];
  const float* qw1 = (const float*)d_in[8];
  const float* kw1 = (const float*)d_in[9];
  const float* vw1 = (const float*)d_in[10];
  const float* pw1 = (const float*)d_in[11];
  const float* pb1 = (const float*)d_in[12];
  const float* cw  = (const float*)d_in[13];
  const float* cb  = (const float*)d_in[14];
  float* out = (float*)d_out;
  char* ws = (char*)d_ws;

  // ws layout (bytes). OM overlays QQ (dead after flash); AMT overlays KK.
  u16*   XT   = (u16*)(ws + 0);          //  2359296  [9216][128] bf16
  u16*   FMT  = (u16*)(ws + 2359296);    //  2359296
  u16*   WALL = (u16*)(ws + 4718592);    //   262144  8 x [128][128] bf16
  u16*   WCV  = (u16*)(ws + 4980736);    //   294912  [9][128][128] bf16
  u16*   QQ   = (u16*)(ws + 5275648);    //  4718592  [2][9216][128] bf16
  u16*   KK   = (u16*)(ws + 9994240);    //  4718592
  u16*   VT   = (u16*)(ws + 14712832);   //  4718592  [2][128][9216] bf16
  float* UU   = (float*)(ws + 19431424); // 28311552  [2][3][9216][128] f32
  float* LL   = (float*)(ws + 47742976); //   221184  [2][3][9216] f32
  u16*   OM   = QQ;                      //  (overlay)
  u16*   AMT  = KK;                      //  (overlay)
  // total 47964160 bytes

  k_transpose<<<dim3(288, 4, 2), 256, 0, stream>>>(x, fm, XT, FMT);
  k_cvtw<<<dim3(64, 8), 256, 0, stream>>>(qw0, kw0, vw0, pw0, qw1, kw1, vw1, pw1, WALL);
  k_cvtconv<<<576, 256, 0, stream>>>(cw, WCV);
  k_qkv<<<dim3(144, 6), 256, 0, stream>>>(XT, FMT, hm, WALL, QQ, KK, VT);
  k_flash<<<432, 256, 0, stream>>>(QQ, KK, VT, UU, LL);
  k_merge<<<2304, 256, 0, stream>>>(UU, LL, OM);
  k_proj<<<576, 256, 0, stream>>>(OM, WALL, pb0, pb1, AMT);
  k_conv<<<576, 256, 0, stream>>>(AMT, WCV, cb, out);
}

// Round 5
// 270.341 us; speedup vs baseline: 3.4039x; 1.8731x over previous
//
#include <hip/hip_runtime.h>

// ---------------------------------------------------------------------------
// Separate_68573447847976: dual masked attention (N=9216, C=128) + 3x3 conv.
// All matmuls via v_mfma_f32_16x16x32_bf16 with verified gfx950 layouts:
//   A-frag: A[m=lane&15][k=quad*8+j]   (16B contiguous in k)
//   B-frag: B[k=quad*8+j][n=lane&15]   (16B contiguous in k of the n-column)
//   C/D   : col=lane&15, row=quad*4+reg
// SCALE*log2(e) folded into Q so softmax uses exp2. No online max (logits
// bounded ~|2| by the 0.02-scaled weights; softmax shift-invariant).
// Flash v5 (LDS-staged): 1152 blocks = qg*16 + attn*8 + ks (XCD-aligned
// combo). Block = 4 waves x 32 q-rows; 36 iters x 32 keys. K/V tiles staged
// cooperatively into padded LDS (K row 272 B, V row 80 B -> all ds_read_b128
// <=2-way, free), double-buffered, ONE barrier/iter, prefetch slack = one
// full iteration. P truncat-packed via v_perm_b32 (bias cancels: l summed
// from same truncated P by MFMA-vs-ONES). Partials U bf16 + L f32 -> k_merge.
// ---------------------------------------------------------------------------

typedef unsigned short u16;
typedef short bf16x8 __attribute__((ext_vector_type(8)));
typedef float f32x4 __attribute__((ext_vector_type(4)));

#define MFMA(a, b, c) __builtin_amdgcn_mfma_f32_16x16x32_bf16((a), (b), (c), 0, 0, 0)

#define NN 9216   // H*W
#define CC 128

__device__ __forceinline__ u16 f2b(float f) {
  union { float f; unsigned int u; } v; v.f = f;
  unsigned int u = v.u + 0x7fffu + ((v.u >> 16) & 1u);  // RNE
  return (u16)(u >> 16);
}

__device__ __forceinline__ unsigned int f2b2(float lo, float hi) {
  return (unsigned int)f2b(lo) | ((unsigned int)f2b(hi) << 16);
}

// pack {hi16(bits(b)), hi16(bits(a))} in ONE v_perm_b32 (truncating bf16)
__device__ __forceinline__ unsigned int pkhi(float a, float b) {
  return __builtin_amdgcn_perm(__float_as_uint(b), __float_as_uint(a), 0x07060302u);
}

__device__ __forceinline__ bf16x8 ldb(const u16* p) { return *(const bf16x8*)p; }

// ---------------- prep: transpose [C][N] f32 -> [N][C] bf16 ----------------
__global__ void k_transpose(const float* __restrict__ x, const float* __restrict__ fm,
                            u16* __restrict__ xt, u16* __restrict__ fmt) {
  __shared__ float tile[32][33];
  const float* src = blockIdx.z ? fm : x;
  u16* dst = blockIdx.z ? fmt : xt;
  int n0 = blockIdx.x * 32, c0 = blockIdx.y * 32;
  int tx = threadIdx.x & 31, ty = threadIdx.x >> 5;  // 32 x 8
#pragma unroll
  for (int i = 0; i < 4; i++)
    tile[ty + i * 8][tx] = src[(c0 + ty + i * 8) * NN + n0 + tx];
  __syncthreads();
#pragma unroll
  for (int i = 0; i < 4; i++)
    dst[(n0 + ty + i * 8) * CC + c0 + tx] = f2b(tile[tx][ty + i * 8]);
}

// ---------------- prep: 8 attention weight mats f32 -> bf16 ----------------
__global__ void k_cvtw(const float* s0, const float* s1, const float* s2, const float* s3,
                       const float* s4, const float* s5, const float* s6, const float* s7,
                       u16* __restrict__ dst) {
  const float* arr[8] = {s0, s1, s2, s3, s4, s5, s6, s7};
  int a = blockIdx.y;
  int i = blockIdx.x * 256 + threadIdx.x;  // 64 blocks * 256 = 16384
  dst[a * 16384 + i] = f2b(arr[a][i]);
}

// ---------------- prep: conv_w [o][i][3][3] -> [khkw][o][i] bf16 -----------
__global__ void k_cvtconv(const float* __restrict__ cw, u16* __restrict__ wp) {
  int i = blockIdx.x * 256 + threadIdx.x;  // 576 blocks -> 147456
  int khkw = i >> 14; int rem = i & 16383; int o = rem >> 7; int ii = rem & 127;
  wp[i] = f2b(cw[(o * 128 + ii) * 9 + khkw]);
}

// ---------------- QKV projections (MFMA) -----------------------------------
__global__ __launch_bounds__(256) void k_qkv(
    const u16* __restrict__ xt, const u16* __restrict__ fmt, const float* __restrict__ hm,
    const u16* __restrict__ wall, u16* __restrict__ Q, u16* __restrict__ K,
    u16* __restrict__ Vt) {
  int wid = threadIdx.x >> 6, lane = threadIdx.x & 63;
  int quad = lane >> 4, c = lane & 15;
  int nt = blockIdx.x * 4 + wid;  // 0..575
  int arr = blockIdx.y;
  int attn = arr / 3, kind = arr % 3;  // 0=Q 1=K 2=V
  int nb = nt * 16;
  const u16* A = (kind == 1) ? fmt : xt;
  const u16* W = wall + (attn * 4 + kind) * 16384;

  if (kind < 2) {  // D[n][d]
    bf16x8 af[4];
#pragma unroll
    for (int ks = 0; ks < 4; ks++)
      af[ks] = ldb(A + (nb + c) * CC + ks * 32 + quad * 8);
    float msk[4];
#pragma unroll
    for (int r = 0; r < 4; r++) {
      bool obj = hm[nb + quad * 4 + r] > 0.3f;
      float mv = (attn == 0) ? (obj ? 1.f : 0.01f) : (obj ? 0.01f : 1.f);
      msk[r] = (kind == 0) ? mv * 0.3606737602222409f : mv;  // 0.25*log2(e)
    }
    u16* out = (kind == 0 ? Q : K) + attn * NN * CC;
#pragma unroll
    for (int dt = 0; dt < 8; dt++) {
      f32x4 acc = {0.f, 0.f, 0.f, 0.f};
#pragma unroll
      for (int ks = 0; ks < 4; ks++)
        acc = MFMA(af[ks], ldb(W + (dt * 16 + c) * CC + ks * 32 + quad * 8), acc);
#pragma unroll
      for (int r = 0; r < 4; r++)
        out[(nb + quad * 4 + r) * CC + dt * 16 + c] = f2b(acc[r] * msk[r]);
    }
  } else {  // Vt[d][n]
    bf16x8 bfr[4];
#pragma unroll
    for (int ks = 0; ks < 4; ks++)
      bfr[ks] = ldb(A + (nb + c) * CC + ks * 32 + quad * 8);
    bool obj = hm[nb + c] > 0.3f;
    float mv = (attn == 0) ? (obj ? 1.f : 0.01f) : (obj ? 0.01f : 1.f);
    u16* out = Vt + attn * CC * NN;
#pragma unroll
    for (int dt = 0; dt < 8; dt++) {
      f32x4 acc = {0.f, 0.f, 0.f, 0.f};
#pragma unroll
      for (int ks = 0; ks < 4; ks++)
        acc = MFMA(ldb(W + (dt * 16 + c) * CC + ks * 32 + quad * 8), bfr[ks], acc);
#pragma unroll
      for (int r = 0; r < 4; r++)
        out[(dt * 16 + quad * 4 + r) * NN + nb + c] = f2b(acc[r] * mv);
    }
  }
}

// ---------------- flash v5 (LDS-staged K/V) ---------------------------------
#define FITERS 36
#define KLDS 8704    // 32 rows x 272 B (256 payload + 16 pad)
#define VLDS 10240   // 128 rows x 80 B (64 payload + 16 pad)
__global__ __launch_bounds__(256, 2) void k_flash(
    const u16* __restrict__ Q, const u16* __restrict__ K, const u16* __restrict__ Vt,
    u16* __restrict__ U, float* __restrict__ L) {
  __shared__ __align__(16) char lds[48128];  // K dbuf 17408 | V dbuf 20480 | P 10240
  int tid = threadIdx.x;
  int wid = tid >> 6, lane = tid & 63;
  int quad = lane >> 4, c = lane & 15;
  int b = blockIdx.x;                 // 1152: b = qg*16 + attn*8 + ks
  int qg = b >> 4; int combo = b & 15;
  int attn = combo >> 3; int ks = combo & 7;
  int nb = qg * 128 + wid * 32;       // wave owns 32 q-rows
  const u16* q = Q + attn * NN * CC;
  const u16* kg = K + attn * NN * CC;
  const u16* vg = Vt + attn * CC * NN;
  int kb0 = ks * 1152;

  // staging maps (byte offsets in LDS, element offsets in global)
  int krow = tid >> 4, kch = tid & 15;
  const u16* gkp0 = kg + (kb0 + krow) * CC + kch * 8;
  const u16* gkp1 = gkp0 + 16 * CC;
  int lk0 = krow * 272 + kch * 16, lk1 = lk0 + 16 * 272;
  int vrow = tid >> 2, vqd = tid & 3;
  const u16* gvp0 = vg + vrow * NN + kb0 + vqd * 8;
  const u16* gvp1 = gvp0 + 64 * NN;
  int lv0 = vrow * 80 + vqd * 16, lv1 = lv0 + 64 * 80;

  bf16x8 qf[2][4];
#pragma unroll
  for (int qt = 0; qt < 2; qt++)
#pragma unroll
    for (int k4 = 0; k4 < 4; k4++)
      qf[qt][k4] = ldb(q + (nb + qt * 16 + c) * CC + k4 * 32 + quad * 8);

  const bf16x8 ONES = {(short)0x3F80, (short)0x3F80, (short)0x3F80, (short)0x3F80,
                       (short)0x3F80, (short)0x3F80, (short)0x3F80, (short)0x3F80};

  f32x4 O[2][8];
  f32x4 lacc[2];
#pragma unroll
  for (int qt = 0; qt < 2; qt++) {
#pragma unroll
    for (int dt = 0; dt < 8; dt++) O[qt][dt] = (f32x4){0.f, 0.f, 0.f, 0.f};
    lacc[qt] = (f32x4){0.f, 0.f, 0.f, 0.f};
  }

  char* Pw = lds + 37888 + wid * 2560;  // 32 rows x 80 B

  // prologue: fetch tile 0
  uint4 gk0 = *(const uint4*)gkp0, gk1 = *(const uint4*)gkp1;
  uint4 gv0 = *(const uint4*)gvp0, gv1 = *(const uint4*)gvp1;

  for (int it = 0; it < FITERS; it++) {
    char* kb_lds = lds + ((it & 1) ? KLDS : 0);
    char* vb_lds = lds + 17408 + ((it & 1) ? VLDS : 0);
    *(uint4*)(kb_lds + lk0) = gk0;
    *(uint4*)(kb_lds + lk1) = gk1;
    *(uint4*)(vb_lds + lv0) = gv0;
    *(uint4*)(vb_lds + lv1) = gv1;
    if (it + 1 < FITERS) {  // prefetch next tile (consumed after next barrier)
      gkp0 += 32 * CC; gkp1 += 32 * CC; gvp0 += 32; gvp1 += 32;
      gk0 = *(const uint4*)gkp0; gk1 = *(const uint4*)gkp1;
      gv0 = *(const uint4*)gvp0; gv1 = *(const uint4*)gvp1;
    }
    __syncthreads();

    // K fragments (A-operand of S^T): row = key, 2-way-free bank pattern
    bf16x8 kf[2][4];
#pragma unroll
    for (int kt = 0; kt < 2; kt++)
#pragma unroll
      for (int k4 = 0; k4 < 4; k4++)
        kf[kt][k4] = *(const bf16x8*)(kb_lds + (kt * 16 + c) * 272 + k4 * 64 + quad * 16);

#pragma unroll
    for (int qt = 0; qt < 2; qt++) {
      f32x4 s0 = {0.f, 0.f, 0.f, 0.f}, s1 = {0.f, 0.f, 0.f, 0.f};
#pragma unroll
      for (int k4 = 0; k4 < 4; k4++) {
        s0 = MFMA(kf[0][k4], qf[qt][k4], s0);
        s1 = MFMA(kf[1][k4], qf[qt][k4], s1);
      }
      // exp2 (raw v_exp_f32) + truncate-pack (v_perm) -> P row (q = c)
      uint2 d0, d1;
      d0.x = pkhi(__builtin_amdgcn_exp2f(s0[0]), __builtin_amdgcn_exp2f(s0[1]));
      d0.y = pkhi(__builtin_amdgcn_exp2f(s0[2]), __builtin_amdgcn_exp2f(s0[3]));
      d1.x = pkhi(__builtin_amdgcn_exp2f(s1[0]), __builtin_amdgcn_exp2f(s1[1]));
      d1.y = pkhi(__builtin_amdgcn_exp2f(s1[2]), __builtin_amdgcn_exp2f(s1[3]));
      char* prow = Pw + (qt * 16 + c) * 80;
      *(uint2*)(prow + quad * 8) = d0;        // keys quad*4..+3
      *(uint2*)(prow + 32 + quad * 8) = d1;   // keys 16+quad*4..+3
    }

    // V fragments (B-operand of PV), shared by both qt
    bf16x8 vf[8];
#pragma unroll
    for (int dt = 0; dt < 8; dt++)
      vf[dt] = *(const bf16x8*)(vb_lds + (dt * 16 + c) * 80 + quad * 16);

#pragma unroll
    for (int qt = 0; qt < 2; qt++) {
      bf16x8 pf = *(const bf16x8*)(Pw + (qt * 16 + c) * 80 + quad * 16);
      lacc[qt] = MFMA(pf, ONES, lacc[qt]);   // rowsum of (truncated) P
#pragma unroll
      for (int dt = 0; dt < 8; dt++) O[qt][dt] = MFMA(pf, vf[dt], O[qt][dt]);
    }
  }

  // partial (unnormalized) U bf16 + rowsum L f32
  int p = attn * 8 + ks;
  u16* up = U + (p * NN + nb) * CC;
#pragma unroll
  for (int qt = 0; qt < 2; qt++)
#pragma unroll
    for (int dt = 0; dt < 8; dt++)
#pragma unroll
      for (int r = 0; r < 4; r++)
        up[(qt * 16 + quad * 4 + r) * CC + dt * 16 + c] = f2b(O[qt][dt][r]);
  if (c == 0) {
#pragma unroll
    for (int qt = 0; qt < 2; qt++)
#pragma unroll
      for (int r = 0; r < 4; r++)
        L[p * NN + nb + qt * 16 + quad * 4 + r] = lacc[qt][r];
  }
}

// ---------------- merge 8 key-split partials, normalize, -> bf16 ------------
__global__ void k_merge(const u16* __restrict__ U, const float* __restrict__ L,
                        u16* __restrict__ Om) {
  int t = blockIdx.x * 256 + threadIdx.x;  // 2304 blocks -> 2*9216*32
  int attn = t / (NN * 32); int rem = t % (NN * 32);
  int n = rem >> 5; int d4 = (rem & 31) * 4;
  float a0 = 0.f, a1 = 0.f, a2 = 0.f, a3 = 0.f, l = 0.f;
#pragma unroll
  for (int s = 0; s < 8; s++) {
    int p = attn * 8 + s;
    uint2 u = *(const uint2*)(U + (p * NN + n) * CC + d4);
    a0 += __uint_as_float(u.x << 16);
    a1 += __uint_as_float(u.x & 0xffff0000u);
    a2 += __uint_as_float(u.y << 16);
    a3 += __uint_as_float(u.y & 0xffff0000u);
    l += L[p * NN + n];
  }
  float inv = 1.f / l;
  uint2 pk;
  pk.x = f2b2(a0 * inv, a1 * inv);
  pk.y = f2b2(a2 * inv, a3 * inv);
  *(uint2*)(Om + ((long)attn * NN + n) * CC + d4) = pk;
}

// ---------------- output projection (et split across waves) ----------------
__global__ __launch_bounds__(256) void k_proj(const u16* __restrict__ Om,
                                              const u16* __restrict__ wall,
                                              const float* __restrict__ pb0,
                                              const float* __restrict__ pb1,
                                              u16* __restrict__ amt) {
  int wid = threadIdx.x >> 6, lane = threadIdx.x & 63;
  int quad = lane >> 4, c = lane & 15;
  int nb = blockIdx.x * 16;
  bf16x8 af[2][4];
#pragma unroll
  for (int a = 0; a < 2; a++)
#pragma unroll
    for (int k4 = 0; k4 < 4; k4++)
      af[a][k4] = ldb(Om + ((long)a * NN + nb + c) * CC + k4 * 32 + quad * 8);
  const u16* wpo = wall + 3 * 16384;
  const u16* wpb = wall + 7 * 16384;
#pragma unroll
  for (int eh = 0; eh < 2; eh++) {
    int et = wid * 2 + eh;
    f32x4 acc = {0.f, 0.f, 0.f, 0.f};
#pragma unroll
    for (int k4 = 0; k4 < 4; k4++)
      acc = MFMA(af[0][k4], ldb(wpo + (et * 16 + c) * CC + k4 * 32 + quad * 8), acc);
#pragma unroll
    for (int k4 = 0; k4 < 4; k4++)
      acc = MFMA(af[1][k4], ldb(wpb + (et * 16 + c) * CC + k4 * 32 + quad * 8), acc);
    float bias = pb0[et * 16 + c] + pb1[et * 16 + c];
#pragma unroll
    for (int r = 0; r < 4; r++)
      amt[(nb + quad * 4 + r) * CC + et * 16 + c] = f2b(acc[r] + bias);
  }
}

// ---------------- 3x3 SAME conv (ot split across waves) ---------------------
__global__ __launch_bounds__(256) void k_conv(const u16* __restrict__ amt,
                                              const u16* __restrict__ wp,
                                              const float* __restrict__ cb,
                                              float* __restrict__ out) {
  int wid = threadIdx.x >> 6, lane = threadIdx.x & 63;
  int quad = lane >> 4, c = lane & 15;
  int p = blockIdx.x * 16 + c;
  int h = p / 96, w = p % 96;
  f32x4 acc[2];
  acc[0] = (f32x4){0.f, 0.f, 0.f, 0.f};
  acc[1] = (f32x4){0.f, 0.f, 0.f, 0.f};
  const bf16x8 zv = {0, 0, 0, 0, 0, 0, 0, 0};
#pragma unroll
  for (int kh = 0; kh < 3; kh++)
#pragma unroll
    for (int kw = 0; kw < 3; kw++) {
      int hh = h + kh - 1, ww = w + kw - 1;
      bool valid = (hh >= 0) && (hh < 96) && (ww >= 0) && (ww < 96);
      int sp = hh * 96 + ww;
      const u16* wbase = wp + (kh * 3 + kw) * 16384;
#pragma unroll
      for (int k4 = 0; k4 < 4; k4++) {
        bf16x8 bv = zv;
        if (valid) bv = ldb(amt + sp * CC + k4 * 32 + quad * 8);
#pragma unroll
        for (int oi = 0; oi < 2; oi++) {
          int ot = wid * 2 + oi;
          acc[oi] = MFMA(ldb(wbase + (ot * 16 + c) * CC + k4 * 32 + quad * 8), bv, acc[oi]);
        }
      }
    }
#pragma unroll
  for (int oi = 0; oi < 2; oi++)
#pragma unroll
    for (int r = 0; r < 4; r++) {
      int o = (wid * 2 + oi) * 16 + quad * 4 + r;
      out[o * NN + p] = acc[oi][r] + cb[o];
    }
}

// ---------------- host ------------------------------------------------------
extern "C" void kernel_launch(void* const* d_in, const int* in_sizes, int n_in,
                              void* d_out, int out_size, void* d_ws, size_t ws_size,
                              hipStream_t stream) {
  (void)in_sizes; (void)n_in; (void)out_size; (void)ws_size;
  const float* x   = (const float*)d_in[0];
  const float* fm  = (const float*)d_in[1];
  const float* hm  = (const float*)d_in[2];
  const float* qw0 = (const float*)d_in[3];
  const float* kw0 = (const float*)d_in[4];
  const float* vw0 = (const float*)d_in[5];
  const float* pw0 = (const float*)d_in[6];
  const float* pb0 = (const float*)d_in[7];
  const float* qw1 = (const float*)d_in[8];
  const float* kw1 = (const float*)d_in[9];
  const float* vw1 = (const float*)d_in[10];
  const float* pw1 = (const float*)d_in[11];
  const float* pb1 = (const float*)d_in[12];
  const float* cw  = (const float*)d_in[13];
  const float* cb  = (const float*)d_in[14];
  float* out = (float*)d_out;
  char* ws = (char*)d_ws;

  // ws layout (bytes). OM overlays QQ (dead after flash); AMT overlays KK.
  u16*   XT   = (u16*)(ws + 0);          //  2359296  [9216][128] bf16
  u16*   FMT  = (u16*)(ws + 2359296);    //  2359296
  u16*   WALL = (u16*)(ws + 4718592);    //   262144  8 x [128][128] bf16
  u16*   WCV  = (u16*)(ws + 4980736);    //   294912  [9][128][128] bf16
  u16*   QQ   = (u16*)(ws + 5275648);    //  4718592  [2][9216][128] bf16
  u16*   KK   = (u16*)(ws + 9994240);    //  4718592
  u16*   VT   = (u16*)(ws + 14712832);   //  4718592  [2][128][9216] bf16
  u16*   UU   = (u16*)(ws + 19431424);   // 37748736  [16][9216][128] bf16
  float* LL   = (float*)(ws + 57180160); //   589824  [16][9216] f32
  u16*   OM   = QQ;                      //  (overlay)
  u16*   AMT  = KK;                      //  (overlay)
  // total 57769984 bytes

  k_transpose<<<dim3(288, 4, 2), 256, 0, stream>>>(x, fm, XT, FMT);
  k_cvtw<<<dim3(64, 8), 256, 0, stream>>>(qw0, kw0, vw0, pw0, qw1, kw1, vw1, pw1, WALL);
  k_cvtconv<<<576, 256, 0, stream>>>(cw, WCV);
  k_qkv<<<dim3(144, 6), 256, 0, stream>>>(XT, FMT, hm, WALL, QQ, KK, VT);
  k_flash<<<1152, 256, 0, stream>>>(QQ, KK, VT, UU, LL);
  k_merge<<<2304, 256, 0, stream>>>(UU, LL, OM);
  k_proj<<<576, 256, 0, stream>>>(OM, WALL, pb0, pb1, AMT);
  k_conv<<<576, 256, 0, stream>>>(AMT, WCV, cb, out);
}